// Round 10
// baseline (100.693 us; speedup 1.0000x reference)
//
#include <hip/hip_runtime.h>
#include <hip/hip_bf16.h>
#include <math.h>

#define BATCH 32
#define CIn   32
#define COut  64

typedef __attribute__((ext_vector_type(8))) short bf16x8;
typedef __attribute__((ext_vector_type(4))) float f32x4;

// ws byte offsets
#define OB_T1F  0u           // 20480 ushort
#define OB_ECF  40960u       // 16384 ushort
#define OB_ESF  73728u       // 16384 ushort
#define OB_XTB  106496u      // 1024*4224*2 = 8650752 B  [b][i][kx*66+n] bf16, signs folded
#define OB_PART 8757248u     // 704*2048*4 = 5767168 B

__device__ __forceinline__ ushort f2bf(float f) {
    union { float f; uint u; } v; v.f = f;
    uint r = (v.u + 0x7FFFu + ((v.u >> 16) & 1u)) >> 16;
    return (ushort)r;
}

// native converts (compiler emits v_cvt_pk_bf16_f32)
__device__ __forceinline__ bf16x8 cvt8(f32x4 lo, f32x4 hi) {
    union { __hip_bfloat162 h2[4]; bf16x8 v; } u;
    u.h2[0] = __float22bfloat162_rn(make_float2(lo[0], lo[1]));
    u.h2[1] = __float22bfloat162_rn(make_float2(lo[2], lo[3]));
    u.h2[2] = __float22bfloat162_rn(make_float2(hi[0], hi[1]));
    u.h2[3] = __float22bfloat162_rn(make_float2(hi[2], hi[3]));
    return u.v;
}
__device__ __forceinline__ ushort f2bfn(float f) {
    union { __hip_bfloat16 h; ushort u; } v;
    v.h = __float2bfloat16(f);
    return v.u;
}

#define NB0 0
#define NB1 16
#define NB2 32
#define NB3 48
#define NB4 50

// ---------------------------------------------------------------------------
// Twiddles (unchanged). T1f: y-DFT B-frags, scaled 1/65536.
// Ecf/Esf: x-DFT A-frags: cos / -sin of 2*pi*kxa*x/256.
// ---------------------------------------------------------------------------
__global__ void fno_tw(ushort* __restrict__ T1f, ushort* __restrict__ Ecf,
                       ushort* __restrict__ Esf) {
    const int nb[5] = {NB0, NB1, NB2, NB3, NB4};
    int idx = blockIdx.x * 256 + threadIdx.x;
    const float w0 = 6.28318530717958647692f / 256.0f;
    if (idx < 20480) {
        int i = idx & 7, l = (idx >> 3) & 63, ct = idx >> 9;
        int c = ct / 5, t = ct - 5 * c;
        int k = 32 * c + 8 * (l >> 4) + i;
        int n = nb[t] + (l & 15);
        int ky = n >> 1, s = n & 1;
        int m = (k * ky) & 255;
        float v = s ? -sinf(w0 * (float)m) : cosf(w0 * (float)m);
        T1f[idx] = f2bf(v * (1.0f / 65536.0f));
    }
    if (idx < 16384) {
        int i = idx & 7, l = (idx >> 3) & 63, km = idx >> 9;  // km = ks*4+mt
        int ks = km >> 2, mt = km & 3;
        int xx = ks * 32 + ((l >> 4) << 3) + i;
        int kx = mt * 16 + (l & 15);
        int kxa = (kx < 32) ? kx : kx + 192;
        int m = (xx * kxa) & 255;
        Ecf[idx] = f2bf(cosf(w0 * (float)m));
        Esf[idx] = f2bf(-sinf(w0 * (float)m));
    }
}

// ---------------------------------------------------------------------------
// Fused y-DFT + x-DFT. 512 blocks x 2 planes, all co-resident (2 blocks/CU).
// Per plane: 16 block-coop strips (16 rows x 256 cols, 16KB), dbuf, raw
// s_barrier + counted vmcnt (no vmcnt(0) drains in steady state). Next
// plane's strips 0-1 prefetched BEFORE phase B so HBM streams through it.
// Ec/Es A-frags preloaded to registers -> phase B issues zero VMEM.
// ---------------------------------------------------------------------------
#define STAGE_S(P, S) do {                                                         \
    int s_ = (S);                                                                  \
    float* lb_ = &smx[s_ & 1][0];                                                  \
    const float* gb_ = x + ((size_t)(P) * 256 + s_ * 16) * 256;                    \
    _Pragma("unroll")                                                              \
    for (int jj = 0; jj < 4; ++jj) {                                               \
        int rl_ = w * 4 + jj;                                                      \
        int sg_ = lane ^ (rl_ & 7);          /* 16B-slot swizzle (involution) */   \
        const float* gp_ = gb_ + (size_t)rl_ * 256 + (sg_ << 2);                   \
        char* lp_ = (char*)lb_ + (rl_ << 10);                                      \
        __builtin_amdgcn_global_load_lds(                                          \
            (const __attribute__((address_space(1))) unsigned int*)gp_,            \
            (__attribute__((address_space(3))) unsigned int*)lp_, 16, 0, 0);       \
    } } while (0)

#define WAITV(N) do {                                                              \
    asm volatile("s_waitcnt vmcnt(" #N ")" ::: "memory");                          \
    __builtin_amdgcn_sched_barrier(0); } while (0)

#define WAITL0 do {                                                                \
    asm volatile("s_waitcnt lgkmcnt(0)" ::: "memory");                             \
    __builtin_amdgcn_sched_barrier(0); } while (0)

#define BAR do {                                                                   \
    __builtin_amdgcn_s_barrier();                                                  \
    __builtin_amdgcn_sched_barrier(0); } while (0)

__global__ __launch_bounds__(256, 2)
void fno_fused(const float* __restrict__ x, const ushort* __restrict__ T1f,
               const ushort* __restrict__ Ecf, const ushort* __restrict__ Esf,
               ushort* __restrict__ XTb) {
    __shared__ __align__(16) float smx[2][4096];   // 2 x 16KB strip buffers
    __shared__ __align__(16) ushort Yt[16896];     // 33.8 KB unit-swizzled [66][256]
    __shared__ __align__(16) ushort xtls[4224];    // 8.4 KB epilogue staging
    const int nb[5] = {NB0, NB1, NB2, NB3, NB4};
    const int tid  = threadIdx.x;
    const int lane = tid & 63;
    const int w    = tid >> 6;
    const int r0   = lane & 15;
    const int g    = lane >> 4;
    const int xr   = r0 & 7;
    const int blk  = blockIdx.x;

    // Phase-B A-frags (plane-independent): wave w owns m-tile w. Preload+drain.
    bf16x8 ecr[8], esr[8];
    {
        const bf16x8* ecp = (const bf16x8*)Ecf;
        const bf16x8* esp = (const bf16x8*)Esf;
#pragma unroll
        for (int ks = 0; ks < 8; ++ks) {
            ecr[ks] = ecp[(ks * 4 + w) * 64 + lane];
            esr[ks] = esp[(ks * 4 + w) * 64 + lane];
        }
    }
    // Phase-A B-frags for this wave's n-tiles (wave w -> tile w; w3 adds tile 4)
    bf16x8 bfr0[8], bfr4[8];
    {
        const bf16x8* bp = (const bf16x8*)T1f;
#pragma unroll
        for (int c = 0; c < 8; ++c) bfr0[c] = bp[(c * 5 + w) * 64 + lane];
        if (w == 3) {
#pragma unroll
            for (int c = 0; c < 8; ++c) bfr4[c] = bp[(c * 5 + 4) * 64 + lane];
        }
    }
    WAITV(0);                                      // one-time drain of preloads

    for (int pl = 0; pl < 2; ++pl) {
        const int p = blk * 2 + pl;                // plane = b*CIn + i

        if (pl == 0) {
            STAGE_S(p, 0); STAGE_S(p, 1);
            WAITV(4);                              // own strip-0 loads done
            BAR;                                   // all waves' strip-0 done
        }
        // pl==1: strips 0,1 prefetched last plane; WAITV(0)+BAR already done.

        for (int s = 0; s < 16; ++s) {
            f32x4 a0 = {0, 0, 0, 0}, a4 = {0, 0, 0, 0};
            const char* rowb = (const char*)&smx[s & 1][0] + (r0 << 10);
#pragma unroll
            for (int c = 0; c < 8; ++c) {
                f32x4 lo = *(const f32x4*)(rowb + ((((c << 3) + (g << 1)    ) ^ xr) << 4));
                f32x4 hi = *(const f32x4*)(rowb + ((((c << 3) + (g << 1) + 1) ^ xr) << 4));
                bf16x8 a = cvt8(lo, hi);
                a0 = __builtin_amdgcn_mfma_f32_16x16x32_bf16(a, bfr0[c], a0, 0, 0, 0);
                if (w == 3)
                    a4 = __builtin_amdgcn_mfma_f32_16x16x32_bf16(a, bfr4[c], a4, 0, 0, 0);
            }
            // write this strip's rows of the wave's n-tile(s) to Yt (LDS)
            {
                int xr0 = (s << 4) + (g << 2);
                int n0  = nb[w] + r0;
                int us0 = n0 * 256 + ((((xr0 >> 3) ^ (n0 & 31)) << 3) | (xr0 & 7));
                union { __hip_bfloat162 h[2]; uint2 u; } uu;
                uu.h[0] = __float22bfloat162_rn(make_float2(a0[0], a0[1]));
                uu.h[1] = __float22bfloat162_rn(make_float2(a0[2], a0[3]));
                *(uint2*)&Yt[us0] = uu.u;
                if (w == 3 && r0 >= 14) {          // tile 4: n = 64,65 only
                    int n4  = 50 + r0;
                    int us4 = n4 * 256 + ((((xr0 >> 3) ^ (n4 & 31)) << 3) | (xr0 & 7));
                    union { __hip_bfloat162 h[2]; uint2 u; } vv;
                    vv.h[0] = __float22bfloat162_rn(make_float2(a4[0], a4[1]));
                    vv.h[1] = __float22bfloat162_rn(make_float2(a4[2], a4[3]));
                    *(uint2*)&Yt[us4] = vv.u;
                }
            }
            WAITL0;                                // Yt/smx LDS ops done
            BAR;                                   // B1: all reads of smx[s&1] done
            if (s <= 13) {
                STAGE_S(p, s + 2);                 // overwrite freed buffer
                WAITV(4);                          // own strip s+1 landed
                BAR;                               // B2: all waves' strip s+1 landed
            } else if (s == 14) {
                if (pl == 0) {                     // prefetch next plane strip 0
                    STAGE_S(p + 1, 0);
                    WAITV(4);                      // strip 15 landed (pf in flight)
                } else {
                    WAITV(0);                      // last plane: drain strip 15
                }
                BAR;
            } else {                               // s == 15
                if (pl == 0) STAGE_S(p + 1, 1);    // prefetch next plane strip 1
                // Yt completeness for phase B was ensured by B1 above.
            }
        }

        // ---- Phase B: P1 = Ec.Yt, P2 = Es.Yt (M=64 kx, N=66, K=256; no VMEM) --
        f32x4 P1[5], P2[5];
#pragma unroll
        for (int t = 0; t < 5; ++t) { P1[t] = (f32x4){0,0,0,0}; P2[t] = (f32x4){0,0,0,0}; }

#pragma unroll
        for (int ks = 0; ks < 8; ++ks) {
#pragma unroll
            for (int t = 0; t < 5; ++t) {
                int n = nb[t] + r0;
                bf16x8 b = *(const bf16x8*)&Yt[n * 256 + ((((ks << 2) + g) ^ (n & 31)) << 3)];
                P1[t] = __builtin_amdgcn_mfma_f32_16x16x32_bf16(ecr[ks], b, P1[t], 0, 0, 0);
                P2[t] = __builtin_amdgcn_mfma_f32_16x16x32_bf16(esr[ks], b, P2[t], 0, 0, 0);
            }
        }

        // recombine re/im across lane pairs, fold weights, stage, store
#pragma unroll
        for (int t = 0; t < 5; ++t) {
            int n  = nb[t] + r0;
            int ky = n >> 1, im = n & 1;
#pragma unroll
            for (int j = 0; j < 4; ++j) {
                float v2x = __shfl_xor(P2[t][j], 1);
                if (t == 4 && r0 < 14) continue;
                int kx = w * 16 + 4 * g + j;
                float val = im ? (P1[t][j] + v2x) : (P1[t][j] - v2x);
                float wgt = (kx < 32) ? ((kx == 0 && ky == 0) ? 1.f : 2.f)
                                      : ((ky == 0) ? 0.f : 2.f);
                if (im) wgt = -wgt;                // fold the (-XTi)*Wi sign
                xtls[kx * 66 + n] = f2bfn(wgt * val);
            }
        }
        WAITL0;
        BAR;                                       // xtls complete
        {
            const uint4* srcq = (const uint4*)xtls;
            uint4* dstq = (uint4*)(XTb + (size_t)p * 4224);
            for (int e = tid; e < 528; e += 256) dstq[e] = srcq[e];
        }
        if (pl == 0) {
            WAITV(0);                              // pf strips + stores drained
            BAR;                                   // all waves ready; xtls reads done
        }
    }
}

// ---------------------------------------------------------------------------
// K3: out = XTb @ W. Split-K: 704 blocks = (ic 0..31, sc 0..21), K=192
// (6 MFMA steps). W fp32 in fragment order, packed-converted in-register.
// ---------------------------------------------------------------------------
__global__ __launch_bounds__(256)
void fno_gemm3(const ushort* __restrict__ XTb, const float* __restrict__ Wr,
               const float* __restrict__ Wi, float* __restrict__ part) {
    const int blk = blockIdx.x;
    const int ic  = blk / 22;
    const int sc  = blk - ic * 22;
    const int tid = threadIdx.x;
    const int lane = tid & 63;
    const int w    = tid >> 6;
    const int r0   = lane & 15;
    const int g    = lane >> 4;
    const int o    = (w << 4) + r0;

    const float* wrp = Wr + ((size_t)ic * 64 + o) * 2112 + sc * 96 + 4 * g;
    const float* wip = Wi + ((size_t)ic * 64 + o) * 2112 + sc * 96 + 4 * g;
    const ushort* a0 = XTb + ((size_t)r0 * 32 + ic) * 4224 + sc * 192 + 8 * g;
    const ushort* a1 = a0 + (size_t)16 * 32 * 4224;

    f32x4 acc0 = {0,0,0,0}, acc1 = {0,0,0,0};
#pragma unroll
    for (int st = 0; st < 6; ++st) {
        f32x4 vr = *(const f32x4*)(wrp + st * 16);
        f32x4 vi = *(const f32x4*)(wip + st * 16);
        union { __hip_bfloat162 h2[4]; bf16x8 v; } ub;
        ub.h2[0] = __float22bfloat162_rn(make_float2(vr[0], vi[0]));
        ub.h2[1] = __float22bfloat162_rn(make_float2(vr[1], vi[1]));
        ub.h2[2] = __float22bfloat162_rn(make_float2(vr[2], vi[2]));
        ub.h2[3] = __float22bfloat162_rn(make_float2(vr[3], vi[3]));
        bf16x8 af0 = *(const bf16x8*)(a0 + st * 32);
        bf16x8 af1 = *(const bf16x8*)(a1 + st * 32);
        acc0 = __builtin_amdgcn_mfma_f32_16x16x32_bf16(af0, ub.v, acc0, 0, 0, 0);
        acc1 = __builtin_amdgcn_mfma_f32_16x16x32_bf16(af1, ub.v, acc1, 0, 0, 0);
    }

    float* pp = part + (size_t)blk * 2048;
#pragma unroll
    for (int j = 0; j < 4; ++j) {
        pp[(4 * g + j) * 64 + o]      = acc0[j];
        pp[(16 + 4 * g + j) * 64 + o] = acc1[j];
    }
}

// ---------------------------------------------------------------------------
// Parallel reduce: 256 blocks x 256 thr; block owns 8 outputs, 32-way K-split.
// Fixed summation order -> deterministic.
// ---------------------------------------------------------------------------
__global__ __launch_bounds__(256)
void fno_reduce(const float* __restrict__ part, float* __restrict__ out) {
    __shared__ float red[256];
    const int tid = threadIdx.x;
    const int il  = tid & 7;
    const int js  = tid >> 3;                      // 0..31
    const int idx = blockIdx.x * 8 + il;

    float s = 0.f;
#pragma unroll
    for (int t = 0; t < 22; ++t)
        s += part[(size_t)(js + 32 * t) * 2048 + idx];
    red[tid] = s;
    __syncthreads();

    if (tid < 8) {
        float v = 0.f;
#pragma unroll
        for (int q = 0; q < 32; ++q) v += red[q * 8 + tid];
        out[blockIdx.x * 8 + tid] = v;
    }
}

// ---------------------------------------------------------------------------
extern "C" void kernel_launch(void* const* d_in, const int* in_sizes, int n_in,
                              void* d_out, int out_size, void* d_ws, size_t ws_size,
                              hipStream_t stream) {
    const float* x  = (const float*)d_in[0];
    const float* wr = (const float*)d_in[1];
    const float* wi = (const float*)d_in[2];
    float* out = (float*)d_out;
    char* ws   = (char*)d_ws;

    ushort* T1f = (ushort*)(ws + OB_T1F);
    ushort* Ecf = (ushort*)(ws + OB_ECF);
    ushort* Esf = (ushort*)(ws + OB_ESF);
    ushort* XTb = (ushort*)(ws + OB_XTB);
    float* part = (float*)(ws + OB_PART);

    fno_tw<<<80, 256, 0, stream>>>(T1f, Ecf, Esf);
    fno_fused<<<512, 256, 0, stream>>>(x, T1f, Ecf, Esf, XTb);
    fno_gemm3<<<704, 256, 0, stream>>>(XTb, wr, wi, part);
    fno_reduce<<<256, 256, 0, stream>>>(part, out);
}

// Round 11
// 78.936 us; speedup vs baseline: 1.2756x; 1.2756x over previous
//
#include <hip/hip_runtime.h>
#include <hip/hip_bf16.h>
#include <math.h>

#define BATCH 32
#define CIn   32
#define COut  64

typedef __attribute__((ext_vector_type(8))) short bf16x8;
typedef __attribute__((ext_vector_type(4))) float f32x4;

// ws byte offsets
#define OB_T1F  0u           // 20480 ushort
#define OB_ECF  40960u       // 16384 ushort
#define OB_ESF  73728u       // 16384 ushort
#define OB_XTB  106496u      // 1024*4224*2 = 8650752 B  [b][i][kx*66+n] bf16, signs folded
#define OB_PART 8757248u     // 704*2048*4 = 5767168 B

__device__ __forceinline__ ushort f2bf(float f) {
    union { float f; uint u; } v; v.f = f;
    uint r = (v.u + 0x7FFFu + ((v.u >> 16) & 1u)) >> 16;
    return (ushort)r;
}

// native converts (compiler emits v_cvt_pk_bf16_f32)
__device__ __forceinline__ ushort f2bfn(float f) {
    union { __hip_bfloat16 h; ushort u; } v;
    v.h = __float2bfloat16(f);
    return v.u;
}
__device__ __forceinline__ bf16x8 cvt8(f32x4 lo, f32x4 hi) {
    union { __hip_bfloat162 h2[4]; bf16x8 v; } u;
    u.h2[0] = __float22bfloat162_rn(make_float2(lo[0], lo[1]));
    u.h2[1] = __float22bfloat162_rn(make_float2(lo[2], lo[3]));
    u.h2[2] = __float22bfloat162_rn(make_float2(hi[0], hi[1]));
    u.h2[3] = __float22bfloat162_rn(make_float2(hi[2], hi[3]));
    return u.v;
}

#define NB0 0
#define NB1 16
#define NB2 32
#define NB3 48
#define NB4 50

// ---------------------------------------------------------------------------
// Twiddles. T1f: y-DFT B-frags, scaled 1/65536.
// Ecf/Esf: x-DFT A-frags: cos / -sin of 2*pi*kxa*x/256.
// ---------------------------------------------------------------------------
__global__ void fno_tw(ushort* __restrict__ T1f, ushort* __restrict__ Ecf,
                       ushort* __restrict__ Esf) {
    const int nb[5] = {NB0, NB1, NB2, NB3, NB4};
    int idx = blockIdx.x * 256 + threadIdx.x;
    const float w0 = 6.28318530717958647692f / 256.0f;
    if (idx < 20480) {
        int i = idx & 7, l = (idx >> 3) & 63, ct = idx >> 9;
        int c = ct / 5, t = ct - 5 * c;
        int k = 32 * c + 8 * (l >> 4) + i;
        int n = nb[t] + (l & 15);
        int ky = n >> 1, s = n & 1;
        int m = (k * ky) & 255;
        float v = s ? -sinf(w0 * (float)m) : cosf(w0 * (float)m);
        T1f[idx] = f2bf(v * (1.0f / 65536.0f));
    }
    if (idx < 16384) {
        int i = idx & 7, l = (idx >> 3) & 63, km = idx >> 9;  // km = ks*4+mt
        int ks = km >> 2, mt = km & 3;
        int xx = ks * 32 + ((l >> 4) << 3) + i;
        int kx = mt * 16 + (l & 15);
        int kxa = (kx < 32) ? kx : kx + 192;
        int m = (xx * kxa) & 255;
        Ecf[idx] = f2bf(cosf(w0 * (float)m));
        Esf[idx] = f2bf(-sinf(w0 * (float)m));
    }
}

// ---------------------------------------------------------------------------
// Fused y-DFT + x-DFT, one block per plane. Phase A: wave-local, barrier-free,
// 16 superchunks of (16 rows x 64 cols)/wave = 2 K-steps each; 2 rotating
// 16KB bufs; one lgkmcnt(0) + one vmcnt wait per 10 MFMAs.
// (Round-8 structure — best measured. r9 block-coop rows and r10
//  plane-pipelined variants both regressed: barrier coupling beats any
//  DRAM-page/overlap gains. Keep waves free-running.)
// ---------------------------------------------------------------------------
#define MFMA5(KC, AV)                                                              \
    acc0 = __builtin_amdgcn_mfma_f32_16x16x32_bf16((AV), bfr[(KC)*5+0], acc0, 0,0,0); \
    acc1 = __builtin_amdgcn_mfma_f32_16x16x32_bf16((AV), bfr[(KC)*5+1], acc1, 0,0,0); \
    acc2 = __builtin_amdgcn_mfma_f32_16x16x32_bf16((AV), bfr[(KC)*5+2], acc2, 0,0,0); \
    acc3 = __builtin_amdgcn_mfma_f32_16x16x32_bf16((AV), bfr[(KC)*5+3], acc3, 0,0,0); \
    acc4 = __builtin_amdgcn_mfma_f32_16x16x32_bf16((AV), bfr[(KC)*5+4], acc4, 0,0,0);

// stage superchunk SC: wave w loads its 16 rows x 64 cols (4 KB) into
// smx[SC&1] + w*4096B via 4 global_load_lds (linear dest base + lane*16;
// source 16B-slot pre-swizzled with involution s ^ (row&7)).
#define STAGE_SC(SC) do {                                                          \
    int sc_ = (SC);                                                                \
    const float* gb_ = x + ((size_t)p * 256 + (sc_ >> 2) * 64 + w * 16) * 256      \
                         + (sc_ & 3) * 64;                                         \
    char* lb_ = (char*)&smx[sc_ & 1][0] + w * 4096;                                \
    _Pragma("unroll")                                                              \
    for (int j = 0; j < 4; ++j) {                                                  \
        int row_ = 4 * j + (lane >> 4);                                            \
        int sg_  = (lane & 15) ^ (row_ & 7);                                       \
        const float* gp_ = gb_ + (size_t)row_ * 256 + (sg_ << 2);                  \
        char* lp_ = lb_ + j * 1024;                                                \
        __builtin_amdgcn_global_load_lds(                                          \
            (const __attribute__((address_space(1))) unsigned int*)gp_,            \
            (__attribute__((address_space(3))) unsigned int*)lp_, 16, 0, 0);       \
    } } while (0)

// read both K-step A-frags of superchunk SC (4 x b128, XOR-deswizzled)
#define DSR4(SC) do {                                                              \
    const char* db_ = (const char*)&smx[(SC) & 1][0] + w * 4096 + r0 * 256;        \
    f32x4* rp_ = rr[(SC) & 1];                                                     \
    rp_[0] = *(const f32x4*)(db_ + (((((g << 1)    )) ^ xr) << 4));                \
    rp_[1] = *(const f32x4*)(db_ + (((((g << 1) + 1)) ^ xr) << 4));                \
    rp_[2] = *(const f32x4*)(db_ + ((8 + (((g << 1)    ) ^ xr)) << 4));            \
    rp_[3] = *(const f32x4*)(db_ + ((8 + (((g << 1) + 1) ^ xr)) << 4));            \
    } while (0)

#define WAITV(N) do {                                                              \
    asm volatile("s_waitcnt vmcnt(" #N ")" ::: "memory");                          \
    __builtin_amdgcn_sched_barrier(0); } while (0)

#define WAITL0 do {                                                                \
    asm volatile("s_waitcnt lgkmcnt(0)" ::: "memory");                             \
    __builtin_amdgcn_sched_barrier(0); } while (0)

// packed Yt write: 4 j-values are 4 consecutive ushorts in one 16B slot
#define YTWP(ACC, T) do {                                                          \
    int n_ = nb[T] + r0;                                                           \
    if ((T) != 4 || r0 >= 14) {                                                    \
        int xr0_ = sl * 64 + w * 16 + 4 * g;                                       \
        int us_ = n_ * 256 + ((((xr0_ >> 3) ^ (n_ & 31)) << 3) | (xr0_ & 7));      \
        union { __hip_bfloat162 h[2]; uint2 u; } uu_;                              \
        uu_.h[0] = __float22bfloat162_rn(make_float2((ACC)[0], (ACC)[1]));         \
        uu_.h[1] = __float22bfloat162_rn(make_float2((ACC)[2], (ACC)[3]));         \
        *(uint2*)&Yt[us_] = uu_.u;                                                 \
    } } while (0)

__global__ __launch_bounds__(256, 2)
void fno_fused(const float* __restrict__ x, const ushort* __restrict__ T1f,
               const ushort* __restrict__ Ecf, const ushort* __restrict__ Esf,
               ushort* __restrict__ XTb) {
    __shared__ float smx[2][4096];                 // 2 x 16KB superchunk bufs
    __shared__ __align__(16) ushort Yt[16896];     // 33.8 KB unit-swizzled [66][256]
    const int nb[5] = {NB0, NB1, NB2, NB3, NB4};
    const int tid  = threadIdx.x;
    const int lane = tid & 63;
    const int w    = tid >> 6;
    const int r0   = lane & 15;
    const int g    = lane >> 4;
    const int xr   = r0 & 7;
    const int p    = blockIdx.x;                   // plane = b*CIn + i

    bf16x8 bfr[40];
    const bf16x8* bp = (const bf16x8*)T1f;
#pragma unroll
    for (int q = 0; q < 40; ++q) bfr[q] = bp[q * 64 + lane];

    f32x4 rr[2][4];                                // reg double-buffer (static idx)

    STAGE_SC(0); STAGE_SC(1);
    WAITV(4);                                      // superchunk 0 staged
    DSR4(0);

    f32x4 acc0, acc1, acc2, acc3, acc4;
#pragma unroll
    for (int it = 0; it < 16; ++it) {
        if ((it & 3) == 0) {
            acc0 = (f32x4){0,0,0,0}; acc1 = (f32x4){0,0,0,0};
            acc2 = (f32x4){0,0,0,0}; acc3 = (f32x4){0,0,0,0};
            acc4 = (f32x4){0,0,0,0};
        }
        WAITL0;                                    // superchunk it's ds_reads done
        if (it + 2 < 16) STAGE_SC(it + 2);         // overwrite buf[it&1] (safe now)
        if (it <= 13)      { WAITV(4); }           // superchunk it+1 landed
        else if (it == 14) { WAITV(0); }
        if (it < 15) DSR4(it + 1);

        bf16x8 a0v = cvt8(rr[it & 1][0], rr[it & 1][1]);
        bf16x8 a1v = cvt8(rr[it & 1][2], rr[it & 1][3]);
        MFMA5(2 * (it & 3)    , a0v);
        MFMA5(2 * (it & 3) + 1, a1v);

        if ((it & 3) == 3) {                       // strip complete -> Yt (LDS)
            int sl = it >> 2;
            YTWP(acc0, 0); YTWP(acc1, 1); YTWP(acc2, 2); YTWP(acc3, 3); YTWP(acc4, 4);
        }
    }
    __syncthreads();

    // ---- Phase B: P1 = Ec . Yt, P2 = Es . Yt  (M=64 kx, N=66, K=256 x) ----
    const int mt = w;
    f32x4 P1[5], P2[5];
#pragma unroll
    for (int t = 0; t < 5; ++t) { P1[t] = (f32x4){0,0,0,0}; P2[t] = (f32x4){0,0,0,0}; }

    const bf16x8* ecp = (const bf16x8*)Ecf;
    const bf16x8* esp = (const bf16x8*)Esf;
#pragma unroll
    for (int ks = 0; ks < 8; ++ks) {
        bf16x8 ea = ecp[(ks * 4 + mt) * 64 + lane];
        bf16x8 es = esp[(ks * 4 + mt) * 64 + lane];
#pragma unroll
        for (int t = 0; t < 5; ++t) {
            int n = nb[t] + r0;
            bf16x8 b = *(const bf16x8*)&Yt[n * 256 + ((((ks << 2) + g) ^ (n & 31)) << 3)];
            P1[t] = __builtin_amdgcn_mfma_f32_16x16x32_bf16(ea, b, P1[t], 0, 0, 0);
            P2[t] = __builtin_amdgcn_mfma_f32_16x16x32_bf16(es, b, P2[t], 0, 0, 0);
        }
    }

    // recombine re/im across lane pairs, fold weights, stage in LDS, store
    ushort* xtl = (ushort*)&smx[0][0];             // 4224 ushort (spans smx)
#pragma unroll
    for (int t = 0; t < 5; ++t) {
        int n  = nb[t] + r0;
        int ky = n >> 1, im = n & 1;
#pragma unroll
        for (int j = 0; j < 4; ++j) {
            float v2x = __shfl_xor(P2[t][j], 1);
            if (t == 4 && r0 < 14) continue;
            int kx = mt * 16 + 4 * g + j;
            float val = im ? (P1[t][j] + v2x) : (P1[t][j] - v2x);
            float wgt = (kx < 32) ? ((kx == 0 && ky == 0) ? 1.f : 2.f)
                                  : ((ky == 0) ? 0.f : 2.f);
            if (im) wgt = -wgt;                    // fold the (-XTi)*Wi sign
            xtl[kx * 66 + n] = f2bfn(wgt * val);
        }
    }
    __syncthreads();

    const uint4* srcq = (const uint4*)xtl;
    uint4* dstq = (uint4*)(XTb + (size_t)p * 4224);
    for (int e = tid; e < 528; e += 256) dstq[e] = srcq[e];
}

// ---------------------------------------------------------------------------
// K3: out = XTb @ W. Split-K: 704 blocks = (ic 0..31, sc 0..21), K=192
// (6 MFMA steps). W fp32 in fragment order, packed-converted in-register.
// ---------------------------------------------------------------------------
__global__ __launch_bounds__(256)
void fno_gemm3(const ushort* __restrict__ XTb, const float* __restrict__ Wr,
               const float* __restrict__ Wi, float* __restrict__ part) {
    const int blk = blockIdx.x;
    const int ic  = blk / 22;
    const int sc  = blk - ic * 22;
    const int tid = threadIdx.x;
    const int lane = tid & 63;
    const int w    = tid >> 6;
    const int r0   = lane & 15;
    const int g    = lane >> 4;
    const int o    = (w << 4) + r0;

    const float* wrp = Wr + ((size_t)ic * 64 + o) * 2112 + sc * 96 + 4 * g;
    const float* wip = Wi + ((size_t)ic * 64 + o) * 2112 + sc * 96 + 4 * g;
    const ushort* a0 = XTb + ((size_t)r0 * 32 + ic) * 4224 + sc * 192 + 8 * g;
    const ushort* a1 = a0 + (size_t)16 * 32 * 4224;

    f32x4 acc0 = {0,0,0,0}, acc1 = {0,0,0,0};
#pragma unroll
    for (int st = 0; st < 6; ++st) {
        f32x4 vr = *(const f32x4*)(wrp + st * 16);
        f32x4 vi = *(const f32x4*)(wip + st * 16);
        union { __hip_bfloat162 h2[4]; bf16x8 v; } ub;
        ub.h2[0] = __float22bfloat162_rn(make_float2(vr[0], vi[0]));
        ub.h2[1] = __float22bfloat162_rn(make_float2(vr[1], vi[1]));
        ub.h2[2] = __float22bfloat162_rn(make_float2(vr[2], vi[2]));
        ub.h2[3] = __float22bfloat162_rn(make_float2(vr[3], vi[3]));
        bf16x8 af0 = *(const bf16x8*)(a0 + st * 32);
        bf16x8 af1 = *(const bf16x8*)(a1 + st * 32);
        acc0 = __builtin_amdgcn_mfma_f32_16x16x32_bf16(af0, ub.v, acc0, 0, 0, 0);
        acc1 = __builtin_amdgcn_mfma_f32_16x16x32_bf16(af1, ub.v, acc1, 0, 0, 0);
    }

    float* pp = part + (size_t)blk * 2048;
#pragma unroll
    for (int j = 0; j < 4; ++j) {
        pp[(4 * g + j) * 64 + o]      = acc0[j];
        pp[(16 + 4 * g + j) * 64 + o] = acc1[j];
    }
}

// ---------------------------------------------------------------------------
// Parallel reduce: 256 blocks x 256 thr; block owns 8 outputs, 32-way K-split.
// Fixed summation order -> deterministic.
// ---------------------------------------------------------------------------
__global__ __launch_bounds__(256)
void fno_reduce(const float* __restrict__ part, float* __restrict__ out) {
    __shared__ float red[256];
    const int tid = threadIdx.x;
    const int il  = tid & 7;
    const int js  = tid >> 3;                      // 0..31
    const int idx = blockIdx.x * 8 + il;

    float s = 0.f;
#pragma unroll
    for (int t = 0; t < 22; ++t)
        s += part[(size_t)(js + 32 * t) * 2048 + idx];
    red[tid] = s;
    __syncthreads();

    if (tid < 8) {
        float v = 0.f;
#pragma unroll
        for (int q = 0; q < 32; ++q) v += red[q * 8 + tid];
        out[blockIdx.x * 8 + tid] = v;
    }
}

// ---------------------------------------------------------------------------
extern "C" void kernel_launch(void* const* d_in, const int* in_sizes, int n_in,
                              void* d_out, int out_size, void* d_ws, size_t ws_size,
                              hipStream_t stream) {
    const float* x  = (const float*)d_in[0];
    const float* wr = (const float*)d_in[1];
    const float* wi = (const float*)d_in[2];
    float* out = (float*)d_out;
    char* ws   = (char*)d_ws;

    ushort* T1f = (ushort*)(ws + OB_T1F);
    ushort* Ecf = (ushort*)(ws + OB_ECF);
    ushort* Esf = (ushort*)(ws + OB_ESF);
    ushort* XTb = (ushort*)(ws + OB_XTB);
    float* part = (float*)(ws + OB_PART);

    fno_tw<<<80, 256, 0, stream>>>(T1f, Ecf, Esf);
    fno_fused<<<1024, 256, 0, stream>>>(x, T1f, Ecf, Esf, XTb);
    fno_gemm3<<<704, 256, 0, stream>>>(XTb, wr, wi, part);
    fno_reduce<<<256, 256, 0, stream>>>(part, out);
}